// Round 2
// baseline (365.556 us; speedup 1.0000x reference)
//
#include <hip/hip_runtime.h>

// ---------------------------------------------------------------------------
// SelfAttention (GN -> QKV 1x1 -> softmax(QK^T/16)V -> proj 1x1 + residual)
// B=8, C=256, GROUPS=32, H=W=64 -> T=4096. fp32 in/out, bf16 MFMA internally.
//
// R2 attention design:
//   - S^T = MFMA(K-frag, Q-frag): C-layout gives 4 consecutive s per lane at
//     fixed q -> P stored with ds_write_b64 into p_lds[q][s] (ldP=72).
//   - S split 1x4 over s (wave w: s in [w*16,+16), all 64 q; Q in 128 VGPR)
//     -> K tile read ONCE from LDS.  PV split 1x4 over c (wave w: c in
//     [w*64,+64)) -> V tile read ONCE; P read 4x.  96 KB reads/block-tile
//     (was 144).
//   - PV uses 32x32x16 MFMA (4061 FLOP/cyc vs 3561).
//   - 3 barriers/tile (separate p_lds removes post-S barrier).
// ---------------------------------------------------------------------------

typedef unsigned short u16;
typedef __attribute__((ext_vector_type(8))) short short8;   // 8 bf16 = 4 VGPR
typedef __attribute__((ext_vector_type(4))) float f32x4;    // 16x16 C/D
typedef __attribute__((ext_vector_type(16))) float f32x16;  // 32x32 C/D

#define MFMA16(a, b, c) __builtin_amdgcn_mfma_f32_16x16x32_bf16((a), (b), (c), 0, 0, 0)
#define MFMA32(a, b, c) __builtin_amdgcn_mfma_f32_32x32x16_bf16((a), (b), (c), 0, 0, 0)

#define GLL16(g, l)                                                            \
  __builtin_amdgcn_global_load_lds(                                            \
      (const __attribute__((address_space(1))) void*)(g),                      \
      (__attribute__((address_space(3))) void*)(l), 16, 0, 0)

__device__ __forceinline__ u16 f2bf(float f) {  // RNE fp32 -> bf16 bits
  union { float f; unsigned u; } v; v.f = f;
  unsigned u = v.u;
  return (u16)((u + 0x7FFFu + ((u >> 16) & 1u)) >> 16);
}

// ---------------------------------------------------------------------------
// 0) weights fp32 -> bf16 (wq|wk|wv|wp contiguous: 4 x 65536)
__global__ __launch_bounds__(256) void conv_w(const float* __restrict__ s0,
                                              const float* __restrict__ s1,
                                              const float* __restrict__ s2,
                                              const float* __restrict__ s3,
                                              u16* __restrict__ dst) {
  const int m = blockIdx.y;
  const float* s = (m == 0) ? s0 : (m == 1) ? s1 : (m == 2) ? s2 : s3;
  const int i = (blockIdx.x * 256 + threadIdx.x) * 4;
  float4 v = *(const float4*)(s + i);
  u16* d = dst + m * 65536 + i;
  d[0] = f2bf(v.x); d[1] = f2bf(v.y); d[2] = f2bf(v.z); d[3] = f2bf(v.w);
}

// ---------------------------------------------------------------------------
// 1) GroupNorm stats: one block per (b,g) contiguous 32768-float chunk.
__global__ __launch_bounds__(256) void gn_stats(const float* __restrict__ x,
                                                float2* __restrict__ stats) {
  const int bg = blockIdx.x;
  const float* p = x + (long)bg * 32768;
  const int tid = threadIdx.x;
  float s = 0.f, ss = 0.f;
  #pragma unroll 8
  for (int i = 0; i < 32; ++i) {
    float4 v = *(const float4*)(p + tid * 4 + i * 1024);
    s  += v.x + v.y + v.z + v.w;
    ss += v.x * v.x + v.y * v.y + v.z * v.z + v.w * v.w;
  }
  for (int off = 32; off; off >>= 1) {
    s  += __shfl_down(s, off);
    ss += __shfl_down(ss, off);
  }
  __shared__ float2 red[4];
  if ((tid & 63) == 0) red[tid >> 6] = make_float2(s, ss);
  __syncthreads();
  if (tid == 0) {
    float S  = red[0].x + red[1].x + red[2].x + red[3].x;
    float SS = red[0].y + red[1].y + red[2].y + red[3].y;
    float mean = S * (1.f / 32768.f);
    float var  = SS * (1.f / 32768.f) - mean * mean;
    stats[bg] = make_float2(mean, rsqrtf(var + 1e-5f));
  }
}

// ---------------------------------------------------------------------------
// 2) normalize + transpose: x (B,C,T) f32 -> h_t (B,T,C) bf16.
__global__ __launch_bounds__(256) void gn_apply(const float* __restrict__ x,
                                                const float2* __restrict__ stats,
                                                const float* __restrict__ gamma,
                                                const float* __restrict__ beta,
                                                u16* __restrict__ h_t) {
  __shared__ float tile[64][65];
  const int tid = threadIdx.x;
  const int b = blockIdx.z, c0 = blockIdx.y * 64, t0 = blockIdx.x * 64;
  {
    const int ci = tid >> 2, tj0 = (tid & 3) * 16;
    const int c = c0 + ci;
    float2 st = stats[b * 32 + (c >> 3)];
    float gm = gamma[c] * st.y;
    float bt = beta[c] - st.x * gm;
    const float* xp = x + ((long)(b * 256 + c) * 4096 + t0 + tj0);
    #pragma unroll
    for (int i = 0; i < 4; ++i) {
      float4 v = *(const float4*)(xp + i * 4);
      tile[ci][tj0 + i * 4 + 0] = v.x * gm + bt;
      tile[ci][tj0 + i * 4 + 1] = v.y * gm + bt;
      tile[ci][tj0 + i * 4 + 2] = v.z * gm + bt;
      tile[ci][tj0 + i * 4 + 3] = v.w * gm + bt;
    }
  }
  __syncthreads();
  {
    const int tj = tid >> 2, ci0 = (tid & 3) * 16;
    u16* hp = h_t + ((long)(b * 4096 + t0 + tj) * 256 + c0 + ci0);
    short8 v0, v1;
    #pragma unroll
    for (int i = 0; i < 8; ++i) v0[i] = (short)f2bf(tile[ci0 + i][tj]);
    #pragma unroll
    for (int i = 0; i < 8; ++i) v1[i] = (short)f2bf(tile[ci0 + 8 + i][tj]);
    *(short8*)hp = v0;
    *(short8*)(hp + 8) = v1;
  }
}

// ---------------------------------------------------------------------------
// gemm_bt core macro-body (128x128 tile, BK=32, 4 waves, XOR granule swizzle).
template <bool ROW_BIAS, bool RESID>
__global__ __launch_bounds__(256, 2) void gemm_bt(
    const u16* __restrict__ A, long strideAz, const u16* __restrict__ B,
    long strideBz, const float* __restrict__ bias, float scale,
    u16* __restrict__ outb, float* __restrict__ outf,
    const float* __restrict__ resid, long strideOz, int N) {
  __shared__ u16 a_lds[128 * 32];
  __shared__ u16 b_lds[128 * 32];
  const int tid = threadIdx.x, w = tid >> 6, l = tid & 63;
  const int l15 = l & 15, l4 = l >> 4;
  const int bz = blockIdx.z;
  A += bz * strideAz;
  B += bz * strideBz;
  const long obase = (long)bz * strideOz;
  const int m0 = blockIdx.y * 128, n0 = blockIdx.x * 128;
  const int wm = (w >> 1) * 64, wn = (w & 1) * 64;

  f32x4 acc[4][4];
  #pragma unroll
  for (int i = 0; i < 4; ++i)
    #pragma unroll
    for (int j = 0; j < 4; ++j) acc[i][j] = (f32x4)0.f;

  for (int kt = 0; kt < 8; ++kt) {
    const int k0 = kt * 32;
    __syncthreads();
    #pragma unroll
    for (int j = 0; j < 2; ++j) {
      const int r0 = (w * 2 + j) * 16;
      const int row = r0 + (l >> 2);
      const int sg = (l & 3) ^ (row & 3);
      GLL16(A + (long)(m0 + row) * 256 + k0 + sg * 8, a_lds + r0 * 32);
      GLL16(B + (long)(n0 + row) * 256 + k0 + sg * 8, b_lds + r0 * 32);
    }
    __syncthreads();
    short8 af[4], bf[4];
    #pragma unroll
    for (int t = 0; t < 4; ++t) {
      const int ra = wm + t * 16 + l15;
      af[t] = *(const short8*)(a_lds + ra * 32 + ((l4 ^ (ra & 3)) * 8));
      const int rb = wn + t * 16 + l15;
      bf[t] = *(const short8*)(b_lds + rb * 32 + ((l4 ^ (rb & 3)) * 8));
    }
    #pragma unroll
    for (int mt = 0; mt < 4; ++mt)
      #pragma unroll
      for (int nt = 0; nt < 4; ++nt) acc[mt][nt] = MFMA16(af[mt], bf[nt], acc[mt][nt]);
  }

  if (!ROW_BIAS) {
    float bv[4];
    #pragma unroll
    for (int nt = 0; nt < 4; ++nt) bv[nt] = bias[n0 + wn + nt * 16 + l15];
    #pragma unroll
    for (int mt = 0; mt < 4; ++mt)
      #pragma unroll
      for (int nt = 0; nt < 4; ++nt)
        #pragma unroll
        for (int r = 0; r < 4; ++r) {
          const int row = m0 + wm + mt * 16 + l4 * 4 + r;
          const int col = n0 + wn + nt * 16 + l15;
          outb[obase + (long)row * N + col] = f2bf((acc[mt][nt][r] + bv[nt]) * scale);
        }
  } else {
    float bm[4][4];
    #pragma unroll
    for (int mt = 0; mt < 4; ++mt)
      #pragma unroll
      for (int r = 0; r < 4; ++r) bm[mt][r] = bias[m0 + wm + mt * 16 + l4 * 4 + r];
    #pragma unroll
    for (int mt = 0; mt < 4; ++mt)
      #pragma unroll
      for (int nt = 0; nt < 4; ++nt)
        #pragma unroll
        for (int r = 0; r < 4; ++r) {
          const int row = m0 + wm + mt * 16 + l4 * 4 + r;
          const int col = n0 + wn + nt * 16 + l15;
          const long idx = obase + (long)row * N + col;
          float v = acc[mt][nt][r] + bm[mt][r];
          if (RESID) outf[idx] = v + resid[idx];
          else       outb[idx] = f2bf(v);
        }
  }
}

// ---------------------------------------------------------------------------
// merged Q+K projection: A (32768x256) x Bw(512x256)^T; cols 0-255 -> Qs
// (scaled 1/16, bias bq), cols 256-511 -> Ks (bias bk). One pass over h_t.
__global__ __launch_bounds__(256, 2) void gemm_qk(
    const u16* __restrict__ A, const u16* __restrict__ Bw,
    const float* __restrict__ bq, const float* __restrict__ bk,
    u16* __restrict__ Qs, u16* __restrict__ Ks) {
  __shared__ u16 a_lds[128 * 32];
  __shared__ u16 b_lds[128 * 32];
  const int tid = threadIdx.x, w = tid >> 6, l = tid & 63;
  const int l15 = l & 15, l4 = l >> 4;
  const int m0 = blockIdx.y * 128, n0 = blockIdx.x * 128;
  const int wm = (w >> 1) * 64, wn = (w & 1) * 64;

  f32x4 acc[4][4];
  #pragma unroll
  for (int i = 0; i < 4; ++i)
    #pragma unroll
    for (int j = 0; j < 4; ++j) acc[i][j] = (f32x4)0.f;

  for (int kt = 0; kt < 8; ++kt) {
    const int k0 = kt * 32;
    __syncthreads();
    #pragma unroll
    for (int j = 0; j < 2; ++j) {
      const int r0 = (w * 2 + j) * 16;
      const int row = r0 + (l >> 2);
      const int sg = (l & 3) ^ (row & 3);
      GLL16(A + (long)(m0 + row) * 256 + k0 + sg * 8, a_lds + r0 * 32);
      GLL16(Bw + (long)(n0 + row) * 256 + k0 + sg * 8, b_lds + r0 * 32);
    }
    __syncthreads();
    short8 af[4], bf[4];
    #pragma unroll
    for (int t = 0; t < 4; ++t) {
      const int ra = wm + t * 16 + l15;
      af[t] = *(const short8*)(a_lds + ra * 32 + ((l4 ^ (ra & 3)) * 8));
      const int rb = wn + t * 16 + l15;
      bf[t] = *(const short8*)(b_lds + rb * 32 + ((l4 ^ (rb & 3)) * 8));
    }
    #pragma unroll
    for (int mt = 0; mt < 4; ++mt)
      #pragma unroll
      for (int nt = 0; nt < 4; ++nt) acc[mt][nt] = MFMA16(af[mt], bf[nt], acc[mt][nt]);
  }

  const bool isQ = n0 < 256;
  u16* out = isQ ? Qs : Ks;
  const float* bias = isQ ? bq : bk;
  const float scale = isQ ? 0.0625f : 1.0f;
  const int nc0 = n0 & 255;
  float bv[4];
  #pragma unroll
  for (int nt = 0; nt < 4; ++nt) bv[nt] = bias[nc0 + wn + nt * 16 + l15];
  #pragma unroll
  for (int mt = 0; mt < 4; ++mt)
    #pragma unroll
    for (int nt = 0; nt < 4; ++nt)
      #pragma unroll
      for (int r = 0; r < 4; ++r) {
        const int row = m0 + wm + mt * 16 + l4 * 4 + r;
        const int col = nc0 + wn + nt * 16 + l15;
        out[(long)row * 256 + col] = f2bf((acc[mt][nt][r] + bv[nt]) * scale);
      }
}

// ---------------------------------------------------------------------------
// attention: block = (batch, 64 Q rows); 64 s-tiles of BN=64 streamed.
// S^T phase: wave w computes s in [w*16,+16) x all 64 q (K read once).
// PV phase:  wave w computes all 64 q x c in [w*64,+64) (V read once).
// P transits p_lds[q][72] (b64 writes / b128 reads, bank-balanced).
// No-max softmax (scores ~N(0,1)); divide by rowsum at the end.
__global__ __launch_bounds__(256, 2) void attn_kernel(
    const u16* __restrict__ Qs, const u16* __restrict__ Ks,
    const u16* __restrict__ Vt, u16* __restrict__ Z) {
  __shared__ u16 k_lds[64 * 256];   // 32 KiB  [s][k granule-swizzled]
  __shared__ u16 v_lds[256 * 64];   // 32 KiB  [c][s granule-swizzled]
  __shared__ u16 p_lds[64 * 72];    // 9 KiB   [q][s], pad 8
  __shared__ float l_red[256];      // per-wave rowsum partials -> inv totals

  const int tid = threadIdx.x, w = tid >> 6, l = tid & 63;
  const int l15 = l & 15, l4 = l >> 4;
  const int l31 = l & 31, h = l >> 5;
  const int bid = blockIdx.x;
  const int batch = bid & 7, qt64 = bid >> 3;  // batch = bid%8: XCD locality
  const long qrow_base = (long)batch * 4096 + qt64 * 64;

  const u16* kbase = Ks + (long)batch * 4096 * 256;
  const u16* vbase = Vt + (long)batch * 256 * 4096;

  // Q fragments (B-operand of S^T): all 64 rows x K=256. 128 VGPR.
  short8 qf[4][8];
  {
    const u16* qp = Qs + qrow_base * 256;
    #pragma unroll
    for (int mt = 0; mt < 4; ++mt)
      #pragma unroll
      for (int ks = 0; ks < 8; ++ks)
        qf[mt][ks] = *(const short8*)(qp + (mt * 16 + l15) * 256 + ks * 32 + l4 * 8);
  }

  f32x16 o_acc[2][2];  // [qt][ct]: rows qt*32.., cols w*64+ct*32..
  #pragma unroll
  for (int i = 0; i < 2; ++i)
    #pragma unroll
    for (int j = 0; j < 2; ++j) o_acc[i][j] = (f32x16)0.f;
  float rs[4] = {0.f, 0.f, 0.f, 0.f};

  for (int st = 0; st < 64; ++st) {
    const int sn0 = st * 64;
    __syncthreads();  // B_pre: PV(st-1) done with k/v/p_lds
    #pragma unroll
    for (int j = 0; j < 8; ++j) {  // K tile: 64 rows x 256
      const int r0 = (j * 4 + w) * 2;
      const int row = r0 + (l >> 5);
      const int sg = (l & 31) ^ (row & 7);
      GLL16(kbase + (long)(sn0 + row) * 256 + sg * 8, k_lds + r0 * 256);
    }
    #pragma unroll
    for (int j = 0; j < 8; ++j) {  // V tile: 256 rows x 64
      const int c0 = (j * 4 + w) * 8;
      const int c = c0 + (l >> 3);
      const int sg = (l & 7) ^ (c & 7);
      GLL16(vbase + (long)c * 4096 + sn0 + sg * 8, v_lds + c0 * 64);
    }
    __syncthreads();  // B_stage: staging drained

    // S^T = K Q^T for s rows [w*16,+16): A = kf (m=s), B = qf (n=q)
    f32x4 sacc[4];
    #pragma unroll
    for (int mt = 0; mt < 4; ++mt) sacc[mt] = (f32x4)0.f;
    const u16* kro = k_lds + (w * 16 + l15) * 256;
    #pragma unroll
    for (int ks = 0; ks < 8; ++ks) {
      short8 kf = *(const short8*)(kro + (((ks * 4 + l4) ^ (l15 & 7)) * 8));
      #pragma unroll
      for (int mt = 0; mt < 4; ++mt) sacc[mt] = MFMA16(kf, qf[mt][ks], sacc[mt]);
    }
    // exp + rowsum + P write: lane holds s = w*16+l4*4+r at q = mt*16+l15
    #pragma unroll
    for (int mt = 0; mt < 4; ++mt) {
      float e0 = __expf(sacc[mt][0]), e1 = __expf(sacc[mt][1]);
      float e2 = __expf(sacc[mt][2]), e3 = __expf(sacc[mt][3]);
      rs[mt] += (e0 + e1) + (e2 + e3);
      ushort4 pk = {f2bf(e0), f2bf(e1), f2bf(e2), f2bf(e3)};
      *(ushort4*)(p_lds + (mt * 16 + l15) * 72 + w * 16 + l4 * 4) = pk;
    }
    __syncthreads();  // B_p: P visible; S-reads of k_lds complete block-wide

    // O += P V (32x32x16): A = P[q][s], B = V[c][s]
    #pragma unroll
    for (int ss = 0; ss < 4; ++ss) {
      short8 pa[2], vb[2];
      #pragma unroll
      for (int qt = 0; qt < 2; ++qt)
        pa[qt] = *(const short8*)(p_lds + (qt * 32 + l31) * 72 + ss * 16 + h * 8);
      #pragma unroll
      for (int ct = 0; ct < 2; ++ct) {
        const int c = w * 64 + ct * 32 + l31;
        const int gv = (ss * 2 + h) ^ (c & 7);
        vb[ct] = *(const short8*)(v_lds + c * 64 + gv * 8);
      }
      #pragma unroll
      for (int qt = 0; qt < 2; ++qt)
        #pragma unroll
        for (int ct = 0; ct < 2; ++ct)
          o_acc[qt][ct] = MFMA32(pa[qt], vb[ct], o_acc[qt][ct]);
    }
  }

  // rowsums: reduce over l4 (s within wave) then across waves via LDS
  #pragma unroll
  for (int mt = 0; mt < 4; ++mt) {
    float v = rs[mt];
    v += __shfl_xor(v, 16);
    v += __shfl_xor(v, 32);
    if (l4 == 0) l_red[w * 64 + mt * 16 + l15] = v;
  }
  __syncthreads();
  if (tid < 64) {
    float t = l_red[tid] + l_red[64 + tid] + l_red[128 + tid] + l_red[192 + tid];
    l_red[tid] = 1.f / t;
  }
  __syncthreads();

  // store Z (B,T,C) bf16. 32x32 C/D: col=l31, row=(reg&3)+8*(reg>>2)+4*h
  #pragma unroll
  for (int qt = 0; qt < 2; ++qt)
    #pragma unroll
    for (int g = 0; g < 4; ++g) {
      const int rbase = qt * 32 + 4 * h + 8 * g;
      float i0 = l_red[rbase + 0], i1 = l_red[rbase + 1];
      float i2 = l_red[rbase + 2], i3 = l_red[rbase + 3];
      #pragma unroll
      for (int ct = 0; ct < 2; ++ct) {
        const int col = w * 64 + ct * 32 + l31;
        u16* zp = Z + (qrow_base + rbase) * 256 + col;
        zp[0]       = f2bf(o_acc[qt][ct][g * 4 + 0] * i0);
        zp[256]     = f2bf(o_acc[qt][ct][g * 4 + 1] * i1);
        zp[512]     = f2bf(o_acc[qt][ct][g * 4 + 2] * i2);
        zp[768]     = f2bf(o_acc[qt][ct][g * 4 + 3] * i3);
      }
    }
}

// ---------------------------------------------------------------------------
extern "C" void kernel_launch(void* const* d_in, const int* in_sizes, int n_in,
                              void* d_out, int out_size, void* d_ws, size_t ws_size,
                              hipStream_t stream) {
  (void)in_sizes; (void)n_in; (void)out_size; (void)ws_size;
  const float* x     = (const float*)d_in[0];
  const float* gamma = (const float*)d_in[1];
  const float* beta  = (const float*)d_in[2];
  const float* wq    = (const float*)d_in[3];
  const float* bq    = (const float*)d_in[4];
  const float* wk    = (const float*)d_in[5];
  const float* bk    = (const float*)d_in[6];
  const float* wv    = (const float*)d_in[7];
  const float* bv    = (const float*)d_in[8];
  const float* wp    = (const float*)d_in[9];
  const float* bp    = (const float*)d_in[10];
  float* out = (float*)d_out;

  char* ws = (char*)d_ws;
  u16*    wb    = (u16*)(ws);                  // 4 x 65536 bf16 (wq|wk|wv|wp)
  float2* stats = (float2*)(ws + 524288);      // 256 x float2
  u16*    h_t   = (u16*)(ws + 526336);         // (B,T,C) bf16
  u16*    Qs    = (u16*)(ws + 17303552);       // (B,T,C) bf16, prescaled /16
  u16*    Ks    = (u16*)(ws + 34080768);       // (B,T,C) bf16
  u16*    Vt    = (u16*)(ws + 50857984);       // (B,C,T) bf16
  u16*    Zb    = (u16*)(ws + 67635200);       // (B,T,C) bf16

  conv_w<<<dim3(64, 4), dim3(256), 0, stream>>>(wq, wk, wv, wp, wb);
  gn_stats<<<dim3(256), dim3(256), 0, stream>>>(x, stats);
  gn_apply<<<dim3(64, 4, 8), dim3(256), 0, stream>>>(x, stats, gamma, beta, h_t);

  const long sB = 4096L * 256L, sO = 256L * 4096L;
  // Q+K merged: (32768x256) x (512x256)^T, one pass over h_t
  gemm_qk<<<dim3(4, 256), dim3(256), 0, stream>>>(h_t, wb, bq, bk, Qs, Ks);
  // V^T per batch: (256x256) x (4096x256)^T -> (B,C,T)
  gemm_bt<true, false><<<dim3(32, 2, 8), dim3(256), 0, stream>>>(
      wb + 2 * 65536, 0L, h_t, sB, bv, 1.0f, Vt, nullptr, nullptr, sO, 4096);

  attn_kernel<<<dim3(512), dim3(256), 0, stream>>>(Qs, Ks, Vt, Zb);

  // proj per batch + bias + residual -> fp32 out (B,C,T)
  gemm_bt<true, true><<<dim3(32, 2, 8), dim3(256), 0, stream>>>(
      wb + 3 * 65536, 0L, Zb, sB, bp, 1.0f, nullptr, out, x, sO, 4096);
}